// Round 2
// baseline (1078.756 us; speedup 1.0000x reference)
//
#include <hip/hip_runtime.h>
#include <hip/hip_bf16.h>

typedef __bf16 bf16x8 __attribute__((ext_vector_type(8)));
typedef float  f32x4  __attribute__((ext_vector_type(4)));

#define DEVI __device__ __forceinline__

DEVI void async_copy16(const void* g, void* s) {
  __builtin_amdgcn_global_load_lds(
      (__attribute__((address_space(1))) void*)g,
      (__attribute__((address_space(3))) void*)s,
      16, 0, 0);
}

// ---------------------------------------------------------------------------
// elementwise f32 -> bf16
__global__ __launch_bounds__(256) void cvt_f32_bf16(const float* __restrict__ in,
                                                    __hip_bfloat16* __restrict__ out,
                                                    int n) {
  int i = (blockIdx.x * 256 + threadIdx.x) * 4;
  if (i >= n) return;
  float4 v = *(const float4*)(in + i);
  union { __hip_bfloat16 h[4]; ushort4 u; } o;
  o.h[0] = __float2bfloat16(v.x);
  o.h[1] = __float2bfloat16(v.y);
  o.h[2] = __float2bfloat16(v.z);
  o.h[3] = __float2bfloat16(v.w);
  *(ushort4*)(out + i) = o.u;
}

// ---------------------------------------------------------------------------
// W (Kdim x Ndim f32, row-major) -> WT (Ndim x Kdim bf16, row-major)
__global__ __launch_bounds__(256) void transpose_cvt(const float* __restrict__ W,
                                                     __hip_bfloat16* __restrict__ WT,
                                                     int Kdim, int Ndim) {
  __shared__ float tile[32][33];
  int bx = blockIdx.x * 32;  // n base
  int by = blockIdx.y * 32;  // k base
  int tx = threadIdx.x;      // 0..31
  int ty = threadIdx.y;      // 0..7
  #pragma unroll
  for (int j = 0; j < 32; j += 8)
    tile[ty + j][tx] = W[(size_t)(by + ty + j) * Ndim + bx + tx];
  __syncthreads();
  #pragma unroll
  for (int j = 0; j < 32; j += 8)
    WT[(size_t)(bx + ty + j) * Kdim + by + tx] = __float2bfloat16(tile[tx][ty + j]);
}

// ---------------------------------------------------------------------------
// C = A @ B  with A: MxK bf16 row-major, BT: NxK bf16 row-major (B^T)
// 128x128 tile, BK=32, 4 waves (each 64x64 = 4x4 16x16 frags)
// EPI 0: f32 store; 1: bf16 store (*scale); 2: bf16 store with fused RoPE (*scale)
template <int EPI>
__global__ __launch_bounds__(256) void gemm_bt(
    const __hip_bfloat16* __restrict__ A,
    const __hip_bfloat16* __restrict__ BT,
    float* __restrict__ Cf,
    __hip_bfloat16* __restrict__ Cb,
    int M, int N, int K,
    const float* __restrict__ fcos,
    const float* __restrict__ fsin,
    float scale) {
  __shared__ alignas(16) __hip_bfloat16 lds[8192];  // A tile 0..4095, B tile 4096..8191
  const int tid = threadIdx.x;
  const int w = tid >> 6, l = tid & 63;
  const int l4 = l >> 4, l15 = l & 15;
  const int wr = w >> 1, wc = w & 1;
  const int rowBase = blockIdx.y * 128;
  const int colBase = blockIdx.x * 128;

  // staging: tile is 512 x 16B chunks per matrix; chunk c -> row c>>2, phys slot c&3,
  // logical k-block = (c&3) ^ ((row>>1)&3)  (XOR swizzle, read side matches)
  const __hip_bfloat16* aSrc[2];
  const __hip_bfloat16* bSrc[2];
  int dstOff[2];
  #pragma unroll
  for (int i = 0; i < 2; i++) {
    int c = i * 256 + tid;
    int r = c >> 2;
    int kb = (c & 3) ^ ((r >> 1) & 3);
    aSrc[i] = A  + (size_t)(rowBase + r) * K + kb * 8;
    bSrc[i] = BT + (size_t)(colBase + r) * K + kb * 8;
    dstOff[i] = (i * 256 + w * 64) * 16;  // wave-uniform LDS base
  }

  f32x4 acc[4][4];
  #pragma unroll
  for (int mi = 0; mi < 4; mi++)
    #pragma unroll
    for (int ni = 0; ni < 4; ni++)
      acc[mi][ni] = (f32x4){0.f, 0.f, 0.f, 0.f};

  for (int k0 = 0; k0 < K; k0 += 32) {
    __syncthreads();
    #pragma unroll
    for (int i = 0; i < 2; i++) {
      async_copy16(aSrc[i] + k0, (char*)lds + dstOff[i]);
      async_copy16(bSrc[i] + k0, (char*)lds + 8192 + dstOff[i]);
    }
    __syncthreads();

    bf16x8 aF[4], bF[4];
    #pragma unroll
    for (int mi = 0; mi < 4; mi++) {
      int row = wr * 64 + mi * 16 + l15;
      int phys = l4 ^ ((row >> 1) & 3);
      aF[mi] = *(const bf16x8*)((const char*)lds + row * 64 + phys * 16);
    }
    #pragma unroll
    for (int ni = 0; ni < 4; ni++) {
      int row = wc * 64 + ni * 16 + l15;
      int phys = l4 ^ ((row >> 1) & 3);
      bF[ni] = *(const bf16x8*)((const char*)lds + 8192 + row * 64 + phys * 16);
    }
    #pragma unroll
    for (int mi = 0; mi < 4; mi++)
      #pragma unroll
      for (int ni = 0; ni < 4; ni++)
        acc[mi][ni] = __builtin_amdgcn_mfma_f32_16x16x32_bf16(aF[mi], bF[ni], acc[mi][ni], 0, 0, 0);
  }

  // epilogue: C/D layout col = lane&15, row = (lane>>4)*4 + reg  [m89-verified]
  const int orow0 = rowBase + wr * 64 + l4 * 4;
  const int ocol0 = colBase + wc * 64 + l15;
  #pragma unroll
  for (int mi = 0; mi < 4; mi++) {
    #pragma unroll
    for (int ni = 0; ni < 4; ni++) {
      #pragma unroll
      for (int reg = 0; reg < 4; reg++) {
        int r = orow0 + mi * 16 + reg;
        int col = ocol0 + ni * 16;
        float v = acc[mi][ni][reg];
        if constexpr (EPI == 0) {
          Cf[(size_t)r * N + col] = v;
        } else if constexpr (EPI == 1) {
          Cb[(size_t)r * N + col] = __float2bfloat16(v * scale);
        } else {
          // RoPE: pair (even,odd) cols live in lanes l, l^1 (same row)
          float p = __shfl_xor(v, 1);
          int dd = col & 127;     // dim within head
          int fi = dd >> 1;
          int srow = r & 2047;    // position in sequence (pos==0)
          float c = fcos[srow * 64 + fi];
          float s = fsin[srow * 64 + fi];
          float outv = ((col & 1) == 0) ? (v * c - p * s) : (p * s + v * c);
          Cb[(size_t)r * N + col] = __float2bfloat16(outv * scale);
        }
      }
    }
  }
}

// ---------------------------------------------------------------------------
// flash attention: grid (S/64, H, B), 4 waves x 16 q-rows, KV tiles of 32
__global__ __launch_bounds__(256) void attn_kernel(
    const __hip_bfloat16* __restrict__ Q,   // [B*S][H*D]  roped, pre-scaled 1/sqrt(D)
    const __hip_bfloat16* __restrict__ Kb,  // [B*S][KVH*D] roped
    const __hip_bfloat16* __restrict__ Vb,  // [B*S][KVH*D]
    __hip_bfloat16* __restrict__ O) {       // [B*S][H*D]
  const int S = 2048, HD = 4096, KVD = 1024, D = 128;
  const int qt = blockIdx.x, h = blockIdx.y, b = blockIdx.z;
  const int kvh = h >> 2;
  const int tid = threadIdx.x;
  const int w = tid >> 6, l = tid & 63;
  const int l4 = l >> 4, l15 = l & 15;

  __shared__ alignas(16) __hip_bfloat16 Kt[32 * 128];   // swizzled row-major
  __shared__ alignas(16) __hip_bfloat16 Vt[128 * 40];   // transposed, padded stride 40
  __shared__ alignas(16) __hip_bfloat16 Pb[4 * 16 * 32];

  // Q fragments: lane holds Q[row = l&15][k = (l>>4)*8 + j] per 32-wide d-chunk
  bf16x8 qf[4];
  {
    const int qrow = qt * 64 + w * 16 + l15;
    const __hip_bfloat16* qptr = Q + (size_t)(b * S + qrow) * HD + h * D + l4 * 8;
    #pragma unroll
    for (int dc = 0; dc < 4; dc++) qf[dc] = *(const bf16x8*)(qptr + dc * 32);
  }

  f32x4 o[8];
  #pragma unroll
  for (int nf = 0; nf < 8; nf++) o[nf] = (f32x4){0.f, 0.f, 0.f, 0.f};
  float m[4]  = {-1e30f, -1e30f, -1e30f, -1e30f};
  float ll[4] = {0.f, 0.f, 0.f, 0.f};

  const int rbase = qt * 64 + w * 16 + l4 * 4;
  char* pbase = (char*)Pb + w * 1024;

  const int nt = 2 * qt + 2;
  for (int t = 0; t < nt; t++) {
    const int kv0 = t * 32;
    __syncthreads();
    // K stage: 512 chunks, swizzled slot = dslot ^ (kvrow&7), via global_load_lds
    #pragma unroll
    for (int i = 0; i < 2; i++) {
      int c = i * 256 + tid;
      int kvr = c >> 4;
      int dslot = (c & 15) ^ (kvr & 7);
      const __hip_bfloat16* src =
          Kb + (size_t)(b * S + kv0 + kvr) * KVD + kvh * D + dslot * 8;
      async_copy16(src, (char*)Kt + (i * 256 + w * 64) * 16);
    }
    // V stage: reg-staged transpose into [d][kv] with padded stride 40
    #pragma unroll
    for (int i = 0; i < 2; i++) {
      int c = i * 256 + tid;
      int kvr = c & 31;
      int dp = (c >> 5) * 8;
      const __hip_bfloat16* src =
          Vb + (size_t)(b * S + kv0 + kvr) * KVD + kvh * D + dp;
      uint4 raw = *(const uint4*)src;
      const __hip_bfloat16* rv = (const __hip_bfloat16*)&raw;
      #pragma unroll
      for (int j = 0; j < 8; j++) Vt[(dp + j) * 40 + kvr] = rv[j];
    }
    __syncthreads();

    // S = Q K^T (pre-scaled)
    f32x4 s0 = (f32x4){0.f, 0.f, 0.f, 0.f};
    f32x4 s1 = (f32x4){0.f, 0.f, 0.f, 0.f};
    #pragma unroll
    for (int dc = 0; dc < 4; dc++) {
      {
        int key = l15;
        int phys = (dc * 4 + l4) ^ (key & 7);
        bf16x8 kf = *(const bf16x8*)((const char*)Kt + key * 256 + phys * 16);
        s0 = __builtin_amdgcn_mfma_f32_16x16x32_bf16(qf[dc], kf, s0, 0, 0, 0);
      }
      {
        int key = 16 + l15;
        int phys = (dc * 4 + l4) ^ (key & 7);
        bf16x8 kf = *(const bf16x8*)((const char*)Kt + key * 256 + phys * 16);
        s1 = __builtin_amdgcn_mfma_f32_16x16x32_bf16(qf[dc], kf, s1, 0, 0, 0);
      }
    }

    // causal mask + online softmax (rows l4*4+reg, cols l15 / 16+l15)
    float alpha[4];
    #pragma unroll
    for (int reg = 0; reg < 4; reg++) {
      int r = rbase + reg;
      if (kv0 + l15 > r)      s0[reg] = -1e30f;
      if (kv0 + 16 + l15 > r) s1[reg] = -1e30f;
      float v = fmaxf(s0[reg], s1[reg]);
      v = fmaxf(v, __shfl_xor(v, 1));
      v = fmaxf(v, __shfl_xor(v, 2));
      v = fmaxf(v, __shfl_xor(v, 4));
      v = fmaxf(v, __shfl_xor(v, 8));
      float mn = fmaxf(m[reg], v);
      alpha[reg] = __expf(m[reg] - mn);
      m[reg] = mn;
      float p0 = __expf(s0[reg] - mn);
      float p1 = __expf(s1[reg] - mn);
      s0[reg] = p0;
      s1[reg] = p1;
      float rs = p0 + p1;
      rs += __shfl_xor(rs, 1);
      rs += __shfl_xor(rs, 2);
      rs += __shfl_xor(rs, 4);
      rs += __shfl_xor(rs, 8);
      ll[reg] = ll[reg] * alpha[reg] + rs;
    }

    // P -> per-wave LDS (bf16, slot-swizzled by (row>>2)&3)
    #pragma unroll
    for (int reg = 0; reg < 4; reg++) {
      int prow = l4 * 4 + reg;
      int sw = ((prow >> 2) & 3) << 4;
      *(__hip_bfloat16*)(pbase + ((prow * 64 + l15 * 2) ^ sw))      = __float2bfloat16(s0[reg]);
      *(__hip_bfloat16*)(pbase + ((prow * 64 + 32 + l15 * 2) ^ sw)) = __float2bfloat16(s1[reg]);
    }

    // rescale O
    #pragma unroll
    for (int nf = 0; nf < 8; nf++)
      #pragma unroll
      for (int reg = 0; reg < 4; reg++) o[nf][reg] *= alpha[reg];

    // O += P @ V
    {
      int sw = ((l15 >> 2) & 3) << 4;
      bf16x8 pa = *(const bf16x8*)(pbase + ((l15 * 64 + l4 * 16) ^ sw));
      #pragma unroll
      for (int nf = 0; nf < 8; nf++) {
        bf16x8 vf = *(const bf16x8*)((const char*)Vt + (nf * 16 + l15) * 80 + l4 * 16);
        o[nf] = __builtin_amdgcn_mfma_f32_16x16x32_bf16(pa, vf, o[nf], 0, 0, 0);
      }
    }
  }

  // normalize + store
  #pragma unroll
  for (int reg = 0; reg < 4; reg++) {
    float inv = 1.0f / ll[reg];
    int r = rbase + reg;
    __hip_bfloat16* optr = O + (size_t)(b * S + r) * HD + h * D + l15;
    #pragma unroll
    for (int nf = 0; nf < 8; nf++) optr[nf * 16] = __float2bfloat16(o[nf][reg] * inv);
  }
}

// ---------------------------------------------------------------------------
extern "C" void kernel_launch(void* const* d_in, const int* in_sizes, int n_in,
                              void* d_out, int out_size, void* d_ws, size_t ws_size,
                              hipStream_t stream) {
  const float* x    = (const float*)d_in[0];
  const float* fcos = (const float*)d_in[2];
  const float* fsin = (const float*)d_in[3];
  const float* wq   = (const float*)d_in[5];
  const float* wk   = (const float*)d_in[6];
  const float* wv   = (const float*)d_in[7];
  const float* wo   = (const float*)d_in[8];
  float* out = (float*)d_out;

  char* ws = (char*)d_ws;
  const size_t MB = 1024 * 1024;
  __hip_bfloat16* xb  = (__hip_bfloat16*)(ws + 0);        // 32MB; reused as ab after GEMMs
  __hip_bfloat16* wT  = (__hip_bfloat16*)(ws + 32 * MB);  // wqT, later woT
  __hip_bfloat16* wkT = (__hip_bfloat16*)(ws + 64 * MB);  // 8MB
  __hip_bfloat16* wvT = (__hip_bfloat16*)(ws + 72 * MB);  // 8MB
  __hip_bfloat16* qb  = (__hip_bfloat16*)(ws + 80 * MB);  // 32MB
  __hip_bfloat16* kb  = (__hip_bfloat16*)(ws + 112 * MB); // 8MB
  __hip_bfloat16* vb  = (__hip_bfloat16*)(ws + 120 * MB); // 8MB
  __hip_bfloat16* ab  = xb;

  const float qscale = 0.08838834764831845f;  // 1/sqrt(128)

  cvt_f32_bf16<<<16384, 256, 0, stream>>>(x, xb, 16777216);
  transpose_cvt<<<dim3(128, 128), dim3(32, 8), 0, stream>>>(wq, wT, 4096, 4096);
  transpose_cvt<<<dim3(32, 128), dim3(32, 8), 0, stream>>>(wk, wkT, 4096, 1024);
  transpose_cvt<<<dim3(32, 128), dim3(32, 8), 0, stream>>>(wv, wvT, 4096, 1024);

  gemm_bt<2><<<dim3(32, 32), 256, 0, stream>>>(xb, wT,  nullptr, qb, 4096, 4096, 4096, fcos, fsin, qscale);
  gemm_bt<2><<<dim3(8, 32),  256, 0, stream>>>(xb, wkT, nullptr, kb, 4096, 1024, 4096, fcos, fsin, 1.0f);
  gemm_bt<1><<<dim3(8, 32),  256, 0, stream>>>(xb, wvT, nullptr, vb, 4096, 1024, 4096, nullptr, nullptr, 1.0f);

  attn_kernel<<<dim3(32, 32, 2), 256, 0, stream>>>(qb, kb, vb, ab);

  transpose_cvt<<<dim3(128, 128), dim3(32, 8), 0, stream>>>(wo, wT, 4096, 4096);
  gemm_bt<0><<<dim3(32, 32), 256, 0, stream>>>(ab, wT, out, nullptr, 4096, 4096, 4096, nullptr, nullptr, 1.0f);
}